// Round 2
// baseline (697.179 us; speedup 1.0000x reference)
//
#include <hip/hip_runtime.h>

// ===========================================================================
// CrossAttention (B=32, TF=2048, TP=256, F=768, P=512, A=512).
// Inputs/outputs are fp32 (per reference); internal GEMMs use bf16 MFMA
// (threshold is ~2% of |ref|max — far above bf16 rounding error).
//
// Pipeline:
//   1. transpose+convert Wq -> WqT [512][768] bf16, Wk -> WkT [512][512] bf16
//   2. GEMM+bias (A fp32 -> bf16 staged): Qbuf = frame @ Wq  [65536][512] bf16
//   3. GEMM+bias: Kp = phn @ Wk  [8192][512] bf16
//   4. transpose per batch: KpT[b] = Kp[b]^T [512][256] bf16
//   5. fused: E = Q K^T + mask -> out1 (fp32); softmax; O = P K;
//             LN(concat(O, Q)) -> out0 (fp32)
// ===========================================================================

typedef __bf16 bf16x8 __attribute__((ext_vector_type(8)));
typedef float  f32x4  __attribute__((ext_vector_type(4)));
typedef int    i32x4  __attribute__((ext_vector_type(4)));
typedef int    i32x2  __attribute__((ext_vector_type(2)));
typedef unsigned short u16;

__device__ __forceinline__ u16 f2b(float f) {   // round-to-nearest-even
  union { float f; unsigned int i; } v; v.f = f;
  unsigned int u = v.i;
  return (u16)((u + 0x7FFFu + ((u >> 16) & 1u)) >> 16);
}
__device__ __forceinline__ float b2f(u16 u) {
  union { unsigned int i; float f; } v; v.i = ((unsigned int)u) << 16; return v.f;
}
__device__ __forceinline__ bf16x8 ldfrag(const u16* p) {
  return __builtin_bit_cast(bf16x8, *(const i32x4*)p);
}
__device__ __forceinline__ f32x4 mfma16(bf16x8 a, bf16x8 b, f32x4 c) {
  return __builtin_amdgcn_mfma_f32_16x16x32_bf16(a, b, c, 0, 0, 0);
}

// --------------------------------------------------------------------------
// out[C][R] (bf16) = in[R][C]^T (fp32). For weights.
// --------------------------------------------------------------------------
__global__ void transpose_f32_bf16(const float* __restrict__ in, u16* __restrict__ out,
                                   int R, int C) {
  __shared__ u16 tile[32][33];
  int c0 = blockIdx.x * 32, r0 = blockIdx.y * 32;
  int x = threadIdx.x, y = threadIdx.y;  // x:0..31, y:0..7
#pragma unroll
  for (int i = 0; i < 32; i += 8) tile[y + i][x] = f2b(in[(size_t)(r0 + y + i) * C + c0 + x]);
  __syncthreads();
#pragma unroll
  for (int i = 0; i < 32; i += 8) out[(size_t)(c0 + y + i) * R + r0 + x] = tile[x][y + i];
}

// --------------------------------------------------------------------------
// bf16 2D transpose, batched via blockIdx.z (for Kp -> KpT).
// --------------------------------------------------------------------------
__global__ void transpose_bf16(const u16* __restrict__ in, u16* __restrict__ out,
                               int R, int C, long inStride, long outStride) {
  __shared__ u16 tile[32][33];
  long bb = blockIdx.z;
  in  += bb * inStride;
  out += bb * outStride;
  int c0 = blockIdx.x * 32, r0 = blockIdx.y * 32;
  int x = threadIdx.x, y = threadIdx.y;
#pragma unroll
  for (int i = 0; i < 32; i += 8) tile[y + i][x] = in[(size_t)(r0 + y + i) * C + c0 + x];
  __syncthreads();
#pragma unroll
  for (int i = 0; i < 32; i += 8) out[(size_t)(c0 + y + i) * R + r0 + x] = tile[x][y + i];
}

// --------------------------------------------------------------------------
// C[M][N] (bf16) = A[M][K] (fp32, converted during staging) @ Bt[N][K]^T (bf16)
// + bias[N] (fp32).  128x128 tile, BK=64, 4 waves each 64x64 quadrant.
// --------------------------------------------------------------------------
__global__ __launch_bounds__(256, 2) void gemm_bias_bt(
    const float* __restrict__ A, const u16* __restrict__ Bt,
    const float* __restrict__ bias, u16* __restrict__ C, int M, int N, int K) {
  __shared__ u16 As[128][72];   // +8 pad: 144B row stride
  __shared__ u16 Bs[128][72];
  int tid = threadIdx.x, wave = tid >> 6, lane = tid & 63;
  int l = lane & 15, q = lane >> 4;
  int wr = wave >> 1, wc = wave & 1;
  int m0 = blockIdx.y * 128, n0 = blockIdx.x * 128;
  int aRow = tid >> 4, aCol = (tid & 15) * 4;       // A: fp32 x4 per thread
  int bRow = tid >> 3, bCol = (tid & 7) * 8;        // B: bf16 x8 per thread

  f32x4 acc[4][4];
#pragma unroll
  for (int mt = 0; mt < 4; mt++)
#pragma unroll
    for (int nt = 0; nt < 4; nt++) acc[mt][nt] = (f32x4)0.0f;

  for (int kc = 0; kc < K; kc += 64) {
    __syncthreads();
#pragma unroll
    for (int i = 0; i < 8; i++) {
      int r = aRow + i * 16;
      f32x4 v = *(const f32x4*)&A[(size_t)(m0 + r) * K + kc + aCol];
      u16 t[4];
#pragma unroll
      for (int j = 0; j < 4; j++) t[j] = f2b(v[j]);
      *(i32x2*)&As[r][aCol] = *(i32x2*)t;
    }
#pragma unroll
    for (int i = 0; i < 4; i++) {
      int r = bRow + i * 32;
      *(i32x4*)&Bs[r][bCol] = *(const i32x4*)&Bt[(size_t)(n0 + r) * K + kc + bCol];
    }
    __syncthreads();
#pragma unroll
    for (int ks = 0; ks < 64; ks += 32) {
      bf16x8 af[4], bv[4];
#pragma unroll
      for (int mt = 0; mt < 4; mt++) af[mt] = ldfrag(&As[wr * 64 + mt * 16 + l][ks + q * 8]);
#pragma unroll
      for (int nt = 0; nt < 4; nt++) bv[nt] = ldfrag(&Bs[wc * 64 + nt * 16 + l][ks + q * 8]);
#pragma unroll
      for (int mt = 0; mt < 4; mt++)
#pragma unroll
        for (int nt = 0; nt < 4; nt++) acc[mt][nt] = mfma16(af[mt], bv[nt], acc[mt][nt]);
    }
  }
  // epilogue: +bias, bf16 store.  D layout: row=q*4+reg, col=l.
#pragma unroll
  for (int nt = 0; nt < 4; nt++) {
    int col = n0 + wc * 64 + nt * 16 + l;
    float bvv = bias[col];
#pragma unroll
    for (int mt = 0; mt < 4; mt++)
#pragma unroll
      for (int r = 0; r < 4; r++) {
        int row = m0 + wr * 64 + mt * 16 + q * 4 + r;
        C[(size_t)row * N + col] = f2b(acc[mt][nt][r] + bvv);
      }
  }
}

// --------------------------------------------------------------------------
// Fused attention per (64-row Q tile, batch). See round-0 notes.
// LDS union: phase1 [Qs 64x72 | Ks 256x72]=46080B ; phase2/3 [Ps 64x264 | Kts 256x40]=54272B
// --------------------------------------------------------------------------
__global__ __launch_bounds__(256, 2) void attn_fused(
    const u16* __restrict__ Qbuf,   // [B*2048][512] bf16
    const u16* __restrict__ Kp,     // [B*256][512] bf16
    const u16* __restrict__ KpT,    // [B][512][256] bf16
    const int* __restrict__ mask,   // [B][256]
    const float* __restrict__ gamma, const float* __restrict__ beta,  // [1024] fp32
    float* __restrict__ out0,       // [B*2048][1024] fp32
    float* __restrict__ out1) {     // [B*2048][256] fp32
  __shared__ __align__(16) char smem[54272];
  u16* Qs  = (u16*)(smem);           // [64][72]
  u16* Ks  = (u16*)(smem + 9216);    // [256][72]
  u16* Ps  = (u16*)(smem);           // [64][264]
  u16* Kts = (u16*)(smem + 33792);   // [256][40]

  int tid = threadIdx.x, wave = tid >> 6, lane = tid & 63;
  int l = lane & 15, q = lane >> 4;
  int m0 = blockIdx.x * 64, b = blockIdx.y;
  const u16* Qb  = Qbuf + ((size_t)b * 2048 + m0) * 512;
  const u16* Kb  = Kp  + (size_t)b * 256 * 512;
  const u16* KTb = KpT + (size_t)b * 512 * 256;

  float madd[16];
#pragma unroll
  for (int nt = 0; nt < 16; nt++)
    madd[nt] = (float)(1 - mask[b * 256 + nt * 16 + l]) * -1000.0f;

  // ---- Phase 1: energy. Wave w owns rows w*16..w*16+15, all 256 cols.
  f32x4 accE[16];
#pragma unroll
  for (int nt = 0; nt < 16; nt++) accE[nt] = (f32x4)0.0f;
  int ldRow = tid >> 3, ldCol = (tid & 7) * 8;
  for (int kc = 0; kc < 512; kc += 64) {
    __syncthreads();
#pragma unroll
    for (int i = 0; i < 2; i++) {
      int r = ldRow + i * 32;
      *(i32x4*)&Qs[r * 72 + ldCol] = *(const i32x4*)&Qb[(size_t)r * 512 + kc + ldCol];
    }
#pragma unroll
    for (int i = 0; i < 8; i++) {
      int r = ldRow + i * 32;
      *(i32x4*)&Ks[r * 72 + ldCol] = *(const i32x4*)&Kb[(size_t)r * 512 + kc + ldCol];
    }
    __syncthreads();
#pragma unroll
    for (int ks = 0; ks < 64; ks += 32) {
      bf16x8 af = ldfrag(&Qs[(wave * 16 + l) * 72 + ks + q * 8]);
#pragma unroll
      for (int nt = 0; nt < 16; nt++) {
        bf16x8 bv = ldfrag(&Ks[(nt * 16 + l) * 72 + ks + q * 8]);
        accE[nt] = mfma16(af, bv, accE[nt]);
      }
    }
  }

  // ---- Phase 2: mask, energy out (fp32), shuffle softmax (quad rows: xor 1/2/4/8)
  int rbase = m0 + wave * 16 + q * 4;
#pragma unroll
  for (int nt = 0; nt < 16; nt++)
#pragma unroll
    for (int r = 0; r < 4; r++) accE[nt][r] += madd[nt];

#pragma unroll
  for (int r = 0; r < 4; r++) {
    size_t rowoff = ((size_t)b * 2048 + rbase + r) * 256;
#pragma unroll
    for (int nt = 0; nt < 16; nt++) out1[rowoff + nt * 16 + l] = accE[nt][r];
  }

  float mx[4], sm[4], rs[4];
#pragma unroll
  for (int r = 0; r < 4; r++) mx[r] = -1e30f;
#pragma unroll
  for (int nt = 0; nt < 16; nt++)
#pragma unroll
    for (int r = 0; r < 4; r++) mx[r] = fmaxf(mx[r], accE[nt][r]);
#pragma unroll
  for (int off = 1; off < 16; off <<= 1)
#pragma unroll
    for (int r = 0; r < 4; r++) mx[r] = fmaxf(mx[r], __shfl_xor(mx[r], off));
#pragma unroll
  for (int r = 0; r < 4; r++) sm[r] = 0.0f;
#pragma unroll
  for (int nt = 0; nt < 16; nt++)
#pragma unroll
    for (int r = 0; r < 4; r++) {
      float p = __expf(accE[nt][r] - mx[r]);
      accE[nt][r] = p;
      sm[r] += p;
    }
#pragma unroll
  for (int off = 1; off < 16; off <<= 1)
#pragma unroll
    for (int r = 0; r < 4; r++) sm[r] += __shfl_xor(sm[r], off);
#pragma unroll
  for (int r = 0; r < 4; r++) rs[r] = 1.0f / sm[r];

  __syncthreads();   // all waves done with Qs/Ks before Ps overwrites
#pragma unroll
  for (int r = 0; r < 4; r++)
#pragma unroll
    for (int nt = 0; nt < 16; nt++)
      Ps[(wave * 16 + q * 4 + r) * 264 + nt * 16 + l] = f2b(accE[nt][r] * rs[r]);

  // ---- Phase 3: O = P @ Kp via KpT.
  f32x4 accO[32];
#pragma unroll
  for (int g = 0; g < 32; g++) accO[g] = (f32x4)0.0f;
  for (int h = 0; h < 2; h++) {
    for (int pc = 0; pc < 256; pc += 32) {
      __syncthreads();
#pragma unroll
      for (int i = 0; i < 4; i++) {
        int r = (tid >> 2) + i * 64, c = (tid & 3) * 8;
        *(i32x4*)&Kts[r * 40 + c] =
            *(const i32x4*)&KTb[(size_t)(h * 256 + r) * 256 + pc + c];
      }
      __syncthreads();
      bf16x8 af = ldfrag(&Ps[(wave * 16 + l) * 264 + pc + q * 8]);
#pragma unroll
      for (int nt = 0; nt < 16; nt++) {
        bf16x8 bv = ldfrag(&Kts[(nt * 16 + l) * 40 + q * 8]);
        accO[h * 16 + nt] = mfma16(af, bv, accO[h * 16 + nt]);
      }
    }
  }

  // ---- Phase 4: LayerNorm over concat(O[512], Q[512]) per row.
  float s1[4], s2[4];
#pragma unroll
  for (int r = 0; r < 4; r++) { s1[r] = 0.0f; s2[r] = 0.0f; }
#pragma unroll
  for (int g = 0; g < 32; g++)
#pragma unroll
    for (int r = 0; r < 4; r++) { float v = accO[g][r]; s1[r] += v; s2[r] += v * v; }
#pragma unroll
  for (int r = 0; r < 4; r++) {
    const u16* qr = Qb + (size_t)(wave * 16 + q * 4 + r) * 512;
#pragma unroll
    for (int p = 0; p < 4; p++) {
      bf16x8 qv = ldfrag(&qr[p * 128 + l * 8]);
#pragma unroll
      for (int j = 0; j < 8; j++) { float v = (float)qv[j]; s1[r] += v; s2[r] += v * v; }
    }
  }
#pragma unroll
  for (int off = 1; off < 16; off <<= 1)
#pragma unroll
    for (int r = 0; r < 4; r++) {
      s1[r] += __shfl_xor(s1[r], off);
      s2[r] += __shfl_xor(s2[r], off);
    }
#pragma unroll
  for (int r = 0; r < 4; r++) {
    float mean = s1[r] * (1.0f / 1024.0f);
    float var  = s2[r] * (1.0f / 1024.0f) - mean * mean;
    float rstd = rsqrtf(var + 1e-5f);
    size_t rowbase = ((size_t)b * 2048 + rbase + r) * 1024;
    // O half (cols 0..511): scalar fp32 stores (64B segments per 16 lanes)
#pragma unroll
    for (int g = 0; g < 32; g++) {
      int col = g * 16 + l;
      out0[rowbase + col] = (accO[g][r] - mean) * rstd * gamma[col] + beta[col];
    }
    // Q half (cols 512..1023): vectorized f32x4 stores
    const u16* qr = Qb + (size_t)(wave * 16 + q * 4 + r) * 512;
#pragma unroll
    for (int p = 0; p < 4; p++) {
      bf16x8 qv = ldfrag(&qr[p * 128 + l * 8]);
      float ov[8];
#pragma unroll
      for (int j = 0; j < 8; j++) {
        int col = 512 + p * 128 + l * 8 + j;
        ov[j] = ((float)qv[j] - mean) * rstd * gamma[col] + beta[col];
      }
      *(f32x4*)&out0[rowbase + 512 + p * 128 + l * 8] = *(f32x4*)&ov[0];
      *(f32x4*)&out0[rowbase + 516 + p * 128 + l * 8] = *(f32x4*)&ov[4];
    }
  }
}

// --------------------------------------------------------------------------
extern "C" void kernel_launch(void* const* d_in, const int* in_sizes, int n_in,
                              void* d_out, int out_size, void* d_ws, size_t ws_size,
                              hipStream_t stream) {
  (void)in_sizes; (void)n_in; (void)out_size; (void)ws_size;
  const float* frame = (const float*)d_in[0];   // [32][2048][768] fp32
  const float* phn   = (const float*)d_in[1];   // [32][256][512]  fp32
  const int*   msk   = (const int*)d_in[2];     // [32][256] int32
  const float* Wq    = (const float*)d_in[3];   // [768][512] fp32
  const float* bq    = (const float*)d_in[4];   // [512]
  const float* Wk    = (const float*)d_in[5];   // [512][512]
  const float* bk    = (const float*)d_in[6];   // [512]
  const float* gamma = (const float*)d_in[7];   // [1024]
  const float* beta  = (const float*)d_in[8];   // [1024]

  u16* ws   = (u16*)d_ws;
  u16* WqT  = ws;              // [512][768] bf16      393216 elems
  u16* WkT  = ws + 393216;     // [512][512]           262144
  u16* Qbuf = ws + 655360;     // [65536][512]         33554432
  u16* Kp   = ws + 34209792;   // [8192][512]          4194304
  u16* KpT  = ws + 38404096;   // [32][512][256]       4194304  (end: 85.2 MB)

  float* out0 = (float*)d_out;                      // [32*2048][1024] fp32
  float* out1 = out0 + (size_t)32 * 2048 * 1024;    // [32*2048][256]  fp32

  transpose_f32_bf16<<<dim3(16, 24, 1), dim3(32, 8, 1), 0, stream>>>(Wq, WqT, 768, 512);
  transpose_f32_bf16<<<dim3(16, 16, 1), dim3(32, 8, 1), 0, stream>>>(Wk, WkT, 512, 512);
  gemm_bias_bt<<<dim3(4, 512, 1), dim3(256, 1, 1), 0, stream>>>(frame, WqT, bq, Qbuf, 65536, 512, 768);
  gemm_bias_bt<<<dim3(4, 64, 1), dim3(256, 1, 1), 0, stream>>>(phn, WkT, bk, Kp, 8192, 512, 512);
  transpose_bf16<<<dim3(16, 8, 32), dim3(32, 8, 1), 0, stream>>>(Kp, KpT, 256, 512, 131072, 131072);
  attn_fused<<<dim3(32, 32, 1), dim3(256, 1, 1), 0, stream>>>(Qbuf, Kp, KpT, msk, gamma, beta, out0, out1);
}